// Round 1
// baseline (1367.699 us; speedup 1.0000x reference)
//
#include <hip/hip_runtime.h>
#include <hip/hip_bf16.h>
#include <math.h>

// Problem constants
#define BB   2
#define CC   256
#define LL   2048
#define DD   64
#define HH   8
#define HDIM 512
#define BLQ  (BB*LL)      // 4096 tokens
#define EPSV 1e-8f
#define NPART 64

// ---------------- wave reduce helpers ----------------
__device__ __forceinline__ float wred_sum(float v) {
#pragma unroll
    for (int off = 32; off > 0; off >>= 1) v += __shfl_down(v, off, 64);
    return v;
}
__device__ __forceinline__ float wred_max(float v) {
#pragma unroll
    for (int off = 32; off > 0; off >>= 1) v = fmaxf(v, __shfl_down(v, off, 64));
    return v;
}

// ---------------- prep: t = x^T + pos_encoding ----------------
// x: (B, C, L) -> t: (B, L, C)
__global__ __launch_bounds__(256) void k_prep(const float* __restrict__ x,
                                              float* __restrict__ t) {
    int idx = blockIdx.x * 256 + threadIdx.x;      // (b, l, c), c fastest
    int c = idx & (CC - 1);
    int l = (idx / CC) & (LL - 1);
    int b = idx / (CC * LL);
    float f = (float)(c & ~1) * (-9.210340371976184f / (float)CC); // -ln(10000)/C * 2i
    float ang = (float)l * expf(f);
    float pe = (c & 1) ? cosf(ang) : sinf(ang);
    t[idx] = x[((size_t)b * CC + c) * LL + l] + pe;
}

// ---------------- generic GEMM: out = alpha*(A @ W^T + bias) + resid ----------------
// A: (M, K) row-major, W: (N, K) row-major, bias: (N), resid/out: (M, N)
// resid may alias out (read-then-write one-to-one per element) -> no restrict there.
#define BM 64
#define BN 64
#define BKT 16
__global__ __launch_bounds__(256) void k_gemm(const float* __restrict__ A,
                                              const float* __restrict__ W,
                                              const float* __restrict__ bias,
                                              const float* resid,
                                              float* out,
                                              int M, int N, int K, float alpha) {
    __shared__ float As[BKT][BM + 4];
    __shared__ float Ws[BKT][BN + 4];
    int tid = threadIdx.x;
    int bm = blockIdx.x * BM;
    int bn = blockIdx.y * BN;
    int tm = (tid >> 4) << 2;
    int tn = (tid & 15) << 2;
    int lr = tid >> 2;            // 0..63
    int lk = (tid & 3) << 2;      // 0,4,8,12
    float acc[4][4] = {};
    for (int k0 = 0; k0 < K; k0 += BKT) {
        float4 a4 = *(const float4*)&A[(size_t)(bm + lr) * K + k0 + lk];
        float4 w4 = *(const float4*)&W[(size_t)(bn + lr) * K + k0 + lk];
        As[lk + 0][lr] = a4.x; As[lk + 1][lr] = a4.y; As[lk + 2][lr] = a4.z; As[lk + 3][lr] = a4.w;
        Ws[lk + 0][lr] = w4.x; Ws[lk + 1][lr] = w4.y; Ws[lk + 2][lr] = w4.z; Ws[lk + 3][lr] = w4.w;
        __syncthreads();
#pragma unroll
        for (int kk = 0; kk < BKT; ++kk) {
            float4 ar = *(const float4*)&As[kk][tm];
            float4 wr = *(const float4*)&Ws[kk][tn];
            float a[4] = {ar.x, ar.y, ar.z, ar.w};
            float w[4] = {wr.x, wr.y, wr.z, wr.w};
#pragma unroll
            for (int i = 0; i < 4; ++i)
#pragma unroll
                for (int j = 0; j < 4; ++j) acc[i][j] += a[i] * w[j];
        }
        __syncthreads();
    }
#pragma unroll
    for (int i = 0; i < 4; ++i) {
        int m = bm + tm + i;
        int n0 = bn + tn;
        float4 r;
        r.x = alpha * (acc[i][0] + bias[n0 + 0]);
        r.y = alpha * (acc[i][1] + bias[n0 + 1]);
        r.z = alpha * (acc[i][2] + bias[n0 + 2]);
        r.w = alpha * (acc[i][3] + bias[n0 + 3]);
        if (resid) {
            float4 rv = *(const float4*)&resid[(size_t)m * N + n0];
            r.x += rv.x; r.y += rv.y; r.z += rv.z; r.w += rv.w;
        }
        *(float4*)&out[(size_t)m * N + n0] = r;
    }
}

// ---------------- attention: 4 queries per block ----------------
#define TQ 4
__global__ __launch_bounds__(256) void k_attn(const float* __restrict__ q,
                                              const float* __restrict__ k,
                                              const float* __restrict__ v,
                                              float* __restrict__ o) {
    int lq0 = blockIdx.x * TQ;
    int h = blockIdx.y;
    int b = blockIdx.z;
    int tid = threadIdx.x;
    __shared__ float sq[TQ][DD];
    __shared__ float sc[TQ][LL];
    __shared__ float red[4];
    __shared__ float part[TQ][4][DD];
    for (int i = tid; i < TQ * DD; i += 256) {
        int qq = i / DD, d = i % DD;
        sq[qq][d] = q[((size_t)(b * LL + lq0 + qq)) * HDIM + h * DD + d];
    }
    __syncthreads();
    const float* kb = k + (size_t)b * LL * HDIM + h * DD;
    float lmax[TQ];
#pragma unroll
    for (int qq = 0; qq < TQ; ++qq) lmax[qq] = -1e30f;
    for (int i = 0; i < LL / 256; ++i) {
        int s = i * 256 + tid;
        const float4* krow = (const float4*)(kb + (size_t)s * HDIM);
        float a[TQ] = {0.f, 0.f, 0.f, 0.f};
#pragma unroll
        for (int d4 = 0; d4 < DD / 4; ++d4) {
            float4 kd = krow[d4];
#pragma unroll
            for (int qq = 0; qq < TQ; ++qq) {
                a[qq] += sq[qq][d4 * 4 + 0] * kd.x + sq[qq][d4 * 4 + 1] * kd.y
                       + sq[qq][d4 * 4 + 2] * kd.z + sq[qq][d4 * 4 + 3] * kd.w;
            }
        }
#pragma unroll
        for (int qq = 0; qq < TQ; ++qq) {
            sc[qq][s] = a[qq];
            lmax[qq] = fmaxf(lmax[qq], a[qq]);
        }
    }
    float m[TQ], sum[TQ];
#pragma unroll
    for (int qq = 0; qq < TQ; ++qq) {
        float w = wred_max(lmax[qq]);
        if ((tid & 63) == 0) red[tid >> 6] = w;
        __syncthreads();
        m[qq] = fmaxf(fmaxf(red[0], red[1]), fmaxf(red[2], red[3]));
        __syncthreads();
    }
    float lsum[TQ] = {0.f, 0.f, 0.f, 0.f};
    for (int i = 0; i < LL / 256; ++i) {
        int s = i * 256 + tid;
#pragma unroll
        for (int qq = 0; qq < TQ; ++qq) {
            float p = __expf(sc[qq][s] - m[qq]);
            sc[qq][s] = p;
            lsum[qq] += p;
        }
    }
#pragma unroll
    for (int qq = 0; qq < TQ; ++qq) {
        float w = wred_sum(lsum[qq]);
        if ((tid & 63) == 0) red[tid >> 6] = w;
        __syncthreads();
        sum[qq] = red[0] + red[1] + red[2] + red[3];
        __syncthreads();
    }
    const float* vb = v + (size_t)b * LL * HDIM + h * DD;
    int d = tid & 63, g = tid >> 6;
    float acc[TQ] = {0.f, 0.f, 0.f, 0.f};
    for (int s = g * (LL / 4); s < (g + 1) * (LL / 4); ++s) {
        float vv = vb[(size_t)s * HDIM + d];
#pragma unroll
        for (int qq = 0; qq < TQ; ++qq) acc[qq] += sc[qq][s] * vv;
    }
#pragma unroll
    for (int qq = 0; qq < TQ; ++qq) part[qq][g][d] = acc[qq];
    __syncthreads();
    {
        int qq = tid >> 6;
        float r = (part[qq][0][d] + part[qq][1][d] + part[qq][2][d] + part[qq][3][d]) / sum[qq];
        o[((size_t)(b * LL + lq0 + qq)) * HDIM + h * DD + d] = r;
    }
}

// ---------------- global-LN stats (2 stage) ----------------
__global__ __launch_bounds__(256) void k_stats1(const float* __restrict__ in,
                                                float* __restrict__ part) {
    int b = blockIdx.y;
    int chunk = blockIdx.x;
    const float4* p = (const float4*)(in + (size_t)b * CC * LL);
    int per = (CC * LL / 4) / NPART;   // 2048 float4 per chunk
    float s = 0.f, s2 = 0.f;
    for (int i = chunk * per + threadIdx.x; i < (chunk + 1) * per; i += 256) {
        float4 vv = p[i];
        s  += vv.x + vv.y + vv.z + vv.w;
        s2 += vv.x * vv.x + vv.y * vv.y + vv.z * vv.z + vv.w * vv.w;
    }
    s = wred_sum(s); s2 = wred_sum(s2);
    __shared__ float rs[4], rs2[4];
    int wv = threadIdx.x >> 6;
    if ((threadIdx.x & 63) == 0) { rs[wv] = s; rs2[wv] = s2; }
    __syncthreads();
    if (threadIdx.x == 0) {
        part[(b * NPART + chunk) * 2 + 0] = rs[0] + rs[1] + rs[2] + rs[3];
        part[(b * NPART + chunk) * 2 + 1] = rs2[0] + rs2[1] + rs2[2] + rs2[3];
    }
}

__global__ __launch_bounds__(64) void k_stats2(const float* __restrict__ part,
                                               float* __restrict__ stats) {
    int b = blockIdx.x;
    int t = threadIdx.x;
    float s  = part[(b * NPART + t) * 2 + 0];
    float s2 = part[(b * NPART + t) * 2 + 1];
    s = wred_sum(s); s2 = wred_sum(s2);
    if (t == 0) {
        float mean = s / (float)(CC * LL);
        float var  = s2 / (float)(CC * LL) - mean * mean;
        stats[b * 2 + 0] = mean;
        stats[b * 2 + 1] = rsqrtf(var + EPSV);
    }
}

// ---------------- LN apply (+optional PReLU, +optional add, optional transpose-out) ----------------
// in may alias out (one-to-one) -> no restrict on those.
__global__ __launch_bounds__(256) void k_ln(const float* in,
                                            const float* __restrict__ g,
                                            const float* __restrict__ be,
                                            const float* __restrict__ stats,
                                            const float* __restrict__ add,
                                            const float* __restrict__ alpha_ptr,
                                            float* out, int transpose_out) {
    int idx = blockIdx.x * 256 + threadIdx.x;
    int c = idx & (CC - 1);
    int b = idx / (CC * LL);
    float mean = stats[b * 2 + 0];
    float inv  = stats[b * 2 + 1];
    float vv = (in[idx] - mean) * inv * g[c] + be[c];
    if (alpha_ptr) {
        float al = alpha_ptr[0];
        vv = vv >= 0.f ? vv : al * vv;
    }
    if (add) vv += add[idx];
    if (transpose_out) {
        int l = (idx / CC) & (LL - 1);
        out[((size_t)b * CC + c) * LL + l] = vv;
    } else {
        out[idx] = vv;
    }
}

// ---------------- launch ----------------
extern "C" void kernel_launch(void* const* d_in, const int* in_sizes, int n_in,
                              void* d_out, int out_size, void* d_ws, size_t ws_size,
                              hipStream_t stream) {
    const float* x      = (const float*)d_in[0];
    const float* Wq     = (const float*)d_in[1];
    const float* bq     = (const float*)d_in[2];
    const float* Wk     = (const float*)d_in[3];
    const float* bk     = (const float*)d_in[4];
    const float* Wv     = (const float*)d_in[5];
    const float* bv     = (const float*)d_in[6];
    const float* Wo     = (const float*)d_in[7];
    const float* bo     = (const float*)d_in[8];
    const float* g_mha  = (const float*)d_in[9];
    const float* b_mha  = (const float*)d_in[10];
    const float* conv_w = (const float*)d_in[11];
    const float* conv_b = (const float*)d_in[12];
    const float* g_ffn  = (const float*)d_in[13];
    const float* b_ffn  = (const float*)d_in[14];
    const float* alpha  = (const float*)d_in[15];
    const float* g_out  = (const float*)d_in[16];
    const float* b_out  = (const float*)d_in[17];
    float* out = (float*)d_out;

    // workspace layout (floats); total ~36 MB
    float* ws   = (float*)d_ws;
    float* t    = ws;                    // 1,048,576  (B,L,C)
    float* qb   = ws + 1048576;          // 2,097,152  (B,L,HD)
    float* kbuf = ws + 3145728;          // 2,097,152
    float* vbuf = ws + 5242880;          // 2,097,152
    float* obuf = ws + 7340032;          // 2,097,152  (ends at 9,437,184)
    float* y    = qb;                    // reuse (q dead after attn)
    float* f    = kbuf;                  // reuse (k dead after attn)
    float* stats = vbuf;                 // 12 floats (v dead after attn)
    float* parts = vbuf + 16;            // 256 floats

    const int nelem = BB * LL * CC;      // 1,048,576
    const float scale = 0.125f;          // 1/sqrt(64)

    k_prep<<<nelem / 256, 256, 0, stream>>>(x, t);

    dim3 gqkv(BLQ / BM, HDIM / BN);
    k_gemm<<<gqkv, 256, 0, stream>>>(t, Wq, bq, nullptr, qb,   BLQ, HDIM, CC, scale);
    k_gemm<<<gqkv, 256, 0, stream>>>(t, Wk, bk, nullptr, kbuf, BLQ, HDIM, CC, 1.f);
    k_gemm<<<gqkv, 256, 0, stream>>>(t, Wv, bv, nullptr, vbuf, BLQ, HDIM, CC, 1.f);

    dim3 gattn(LL / TQ, HH, BB);
    k_attn<<<gattn, 256, 0, stream>>>(qb, kbuf, vbuf, obuf);

    dim3 gout(BLQ / BM, CC / BN);
    k_gemm<<<gout, 256, 0, stream>>>(obuf, Wo, bo, t, t, BLQ, CC, HDIM, 1.f); // t += o@Wo^T+bo

    dim3 gst(NPART, BB);
    k_stats1<<<gst, 256, 0, stream>>>(t, parts);
    k_stats2<<<BB, 64, 0, stream>>>(parts, stats);
    k_ln<<<nelem / 256, 256, 0, stream>>>(t, g_mha, b_mha, stats, nullptr, nullptr, y, 0);

    k_gemm<<<gout, 256, 0, stream>>>(y, conv_w, conv_b, nullptr, f, BLQ, CC, CC, 1.f);

    k_stats1<<<gst, 256, 0, stream>>>(f, parts);
    k_stats2<<<BB, 64, 0, stream>>>(parts, stats + 4);
    // s = prelu(ln(f)) + y, in-place into f
    k_ln<<<nelem / 256, 256, 0, stream>>>(f, g_ffn, b_ffn, stats + 4, y, alpha, f, 0);

    k_stats1<<<gst, 256, 0, stream>>>(f, parts);
    k_stats2<<<BB, 64, 0, stream>>>(parts, stats + 8);
    k_ln<<<nelem / 256, 256, 0, stream>>>(f, g_out, b_out, stats + 8, nullptr, nullptr, out, 1);
}

// Round 2
// 208.105 us; speedup vs baseline: 6.5722x; 6.5722x over previous
//
#include <hip/hip_runtime.h>
#include <hip/hip_bf16.h>
#include <math.h>

// Problem constants
#define BB   2
#define CC   256
#define LL   2048
#define DD   64
#define HH   8
#define HDIM 512
#define BLQ  (BB*LL)      // 4096 tokens
#define EPSV 1e-8f
#define NPART 64

typedef __attribute__((ext_vector_type(8))) short short8;   // 8 bf16 (4 VGPRs)
typedef __attribute__((ext_vector_type(4))) float f32x4;    // MFMA acc

// ---------------- helpers ----------------
__device__ __forceinline__ float wred_sum(float v) {
#pragma unroll
    for (int off = 32; off > 0; off >>= 1) v += __shfl_down(v, off, 64);
    return v;
}

// round-to-nearest-even fp32 -> bf16 (as ushort)
__device__ __forceinline__ unsigned short f2bf(float x) {
    union { float f; unsigned u; } a; a.f = x;
    unsigned r = a.u + 0x7fff + ((a.u >> 16) & 1);
    return (unsigned short)(r >> 16);
}
// pack two floats -> u32 of 2 bf16 (lo = a, hi = b)
__device__ __forceinline__ unsigned pk(float a, float b) {
    return (unsigned)f2bf(a) | ((unsigned)f2bf(b) << 16);
}
// assemble a bf16x8 fragment from two 8B LDS loads (rows may be only 8B aligned)
__device__ __forceinline__ short8 ld_frag(const unsigned short* p) {
    union { short8 v; uint2 u[2]; } f;
    f.u[0] = *(const uint2*)p;
    f.u[1] = *(const uint2*)(p + 4);
    return f.v;
}

// ---------------- prep: t = x^T + pos_encoding ----------------
__global__ __launch_bounds__(256) void k_prep(const float* __restrict__ x,
                                              float* __restrict__ t) {
    int idx = blockIdx.x * 256 + threadIdx.x;      // (b, l, c), c fastest
    int c = idx & (CC - 1);
    int l = (idx / CC) & (LL - 1);
    int b = idx / (CC * LL);
    float f = (float)(c & ~1) * (-9.210340371976184f / (float)CC);
    float ang = (float)l * expf(f);
    float pe = (c & 1) ? cosf(ang) : sinf(ang);
    t[idx] = x[((size_t)b * CC + c) * LL + l] + pe;
}

// ---------------- generic GEMM: out = alpha*(A @ W^T + bias) (+ resid) ----------------
// mode 0: fp32 out (M,N) row-major, optional resid add (may alias out)
// mode 1: bf16 out at [((b*H+h)*L + l)*D + d]  where m=b*L+l, n=h*D+d
#define BM 64
#define BN 64
#define BKT 16
__global__ __launch_bounds__(256) void k_gemm(const float* __restrict__ A,
                                              const float* __restrict__ W,
                                              const float* __restrict__ bias,
                                              const float* resid,
                                              void* outp, int mode,
                                              int M, int N, int K, float alpha) {
    __shared__ float As[BKT][BM + 4];
    __shared__ float Ws[BKT][BN + 4];
    int tid = threadIdx.x;
    int bm = blockIdx.x * BM;
    int bn = blockIdx.y * BN;
    int tm = (tid >> 4) << 2;
    int tn = (tid & 15) << 2;
    int lr = tid >> 2;
    int lk = (tid & 3) << 2;
    float acc[4][4] = {};
    for (int k0 = 0; k0 < K; k0 += BKT) {
        float4 a4 = *(const float4*)&A[(size_t)(bm + lr) * K + k0 + lk];
        float4 w4 = *(const float4*)&W[(size_t)(bn + lr) * K + k0 + lk];
        As[lk + 0][lr] = a4.x; As[lk + 1][lr] = a4.y; As[lk + 2][lr] = a4.z; As[lk + 3][lr] = a4.w;
        Ws[lk + 0][lr] = w4.x; Ws[lk + 1][lr] = w4.y; Ws[lk + 2][lr] = w4.z; Ws[lk + 3][lr] = w4.w;
        __syncthreads();
#pragma unroll
        for (int kk = 0; kk < BKT; ++kk) {
            float4 ar = *(const float4*)&As[kk][tm];
            float4 wr = *(const float4*)&Ws[kk][tn];
            float a[4] = {ar.x, ar.y, ar.z, ar.w};
            float w[4] = {wr.x, wr.y, wr.z, wr.w};
#pragma unroll
            for (int i = 0; i < 4; ++i)
#pragma unroll
                for (int j = 0; j < 4; ++j) acc[i][j] += a[i] * w[j];
        }
        __syncthreads();
    }
    int n0 = bn + tn;
#pragma unroll
    for (int i = 0; i < 4; ++i) {
        int m = bm + tm + i;
        float r0 = alpha * (acc[i][0] + bias[n0 + 0]);
        float r1 = alpha * (acc[i][1] + bias[n0 + 1]);
        float r2 = alpha * (acc[i][2] + bias[n0 + 2]);
        float r3 = alpha * (acc[i][3] + bias[n0 + 3]);
        if (mode == 0) {
            float* out = (float*)outp;
            if (resid) {
                float4 rv = *(const float4*)&resid[(size_t)m * N + n0];
                r0 += rv.x; r1 += rv.y; r2 += rv.z; r3 += rv.w;
            }
            float4 r = {r0, r1, r2, r3};
            *(float4*)&out[(size_t)m * N + n0] = r;
        } else {
            unsigned short* ob = (unsigned short*)outp;
            int b = m >> 11, l = m & (LL - 1);
            int h = n0 >> 6, d0 = n0 & 63;
            uint2 w2;
            w2.x = pk(r0, r1);
            w2.y = pk(r2, r3);
            *(uint2*)&ob[(((size_t)(b * HH + h)) * LL + l) * DD + d0] = w2;
        }
    }
}

// ---------------- V transpose+convert: vbuf fp32 (B,L,H,D) -> Vt bf16 (B,H,D,L) ----------------
__global__ __launch_bounds__(256) void k_vtrans(const float* __restrict__ v,
                                                unsigned short* __restrict__ vt) {
    int l0 = blockIdx.x * 64;
    int h = blockIdx.y, b = blockIdx.z;
    __shared__ float tr[64][65];
    int t = threadIdx.x;
#pragma unroll
    for (int p = 0; p < 4; ++p) {
        int l = p * 16 + (t >> 4);
        int d0 = 4 * (t & 15);
        float4 x = *(const float4*)&v[((size_t)(b * LL + l0 + l)) * HDIM + h * DD + d0];
        tr[d0 + 0][l] = x.x; tr[d0 + 1][l] = x.y; tr[d0 + 2][l] = x.z; tr[d0 + 3][l] = x.w;
    }
    __syncthreads();
#pragma unroll
    for (int p = 0; p < 2; ++p) {
        int d = p * 32 + (t >> 3);
        int l8 = 8 * (t & 7);
        uint4 o;
        o.x = pk(tr[d][l8 + 0], tr[d][l8 + 1]);
        o.y = pk(tr[d][l8 + 2], tr[d][l8 + 3]);
        o.z = pk(tr[d][l8 + 4], tr[d][l8 + 5]);
        o.w = pk(tr[d][l8 + 6], tr[d][l8 + 7]);
        *(uint4*)&vt[(((size_t)(b * HH + h)) * DD + d) * LL + l0 + l8] = o;
    }
}

// ---------------- MFMA flash attention ----------------
// Qbf,Kbf: (B,H,L,D) bf16 ; Vt: (B,H,D,L) bf16 ; o: (B,L,HD) fp32
// Block: 512 thr = 8 waves; wave w owns q rows [bx*128 + w*16, +16); K-tiles of 64.
// S^T = mfma(K_frag, Q_frag)  (col = q = lane&15) ; O^T = mfma(Vt_frag, P^T_frag).
#define SBLK 64
#define LDK  68   // padded LDS stride (elements)
__global__ __launch_bounds__(512) void k_attn(const unsigned short* __restrict__ Qb,
                                              const unsigned short* __restrict__ Kb,
                                              const unsigned short* __restrict__ Vb,
                                              float* __restrict__ o) {
    int h = blockIdx.y, b = blockIdx.z;
    int tid = threadIdx.x;
    int w = tid >> 6, lane = tid & 63;
    int g = lane >> 4, qi = lane & 15;
    int q0 = blockIdx.x * 128 + w * 16;

    __shared__ unsigned short Ks[SBLK][LDK];
    __shared__ unsigned short Vts[DD][LDK];
    __shared__ unsigned short Pw[8][16][LDK];

    const size_t bh = (size_t)(b * HH + h);
    const unsigned short* Qg = Qb + bh * LL * DD;
    const unsigned short* Kg = Kb + bh * LL * DD;
    const unsigned short* Vg = Vb + bh * DD * LL;

    // preload Q fragments: lane holds Q[q0+qi][c*32 + 8g + {0..7}]
    short8 qf[2];
#pragma unroll
    for (int c = 0; c < 2; ++c)
        qf[c] = *(const short8*)&Qg[(size_t)(q0 + qi) * DD + c * 32 + 8 * g];

    f32x4 ot[4];
#pragma unroll
    for (int db = 0; db < 4; ++db) ot[db] = (f32x4){0.f, 0.f, 0.f, 0.f};
    float m = -INFINITY, sum = 0.f;

    int srow = tid & 63;            // K row / Vt row (d)
    int scol = (tid >> 6) * 8;      // element col chunk

    for (int s0 = 0; s0 < LL; s0 += SBLK) {
        uint4 kv = *(const uint4*)&Kg[(size_t)(s0 + srow) * DD + scol];
        uint4 vv = *(const uint4*)&Vg[(size_t)srow * LL + s0 + scol];
        if (s0) __syncthreads();
        *(uint2*)&Ks[srow][scol]      = make_uint2(kv.x, kv.y);
        *(uint2*)&Ks[srow][scol + 4]  = make_uint2(kv.z, kv.w);
        *(uint2*)&Vts[srow][scol]     = make_uint2(vv.x, vv.y);
        *(uint2*)&Vts[srow][scol + 4] = make_uint2(vv.z, vv.w);
        __syncthreads();

        // S^T: 4 s-fragments of 16 rows; lane holds (s = sb*16 + 4g + r, q = qi)
        f32x4 st[4];
#pragma unroll
        for (int sb = 0; sb < 4; ++sb) {
            f32x4 acc = (f32x4){0.f, 0.f, 0.f, 0.f};
#pragma unroll
            for (int c = 0; c < 2; ++c) {
                short8 kf = ld_frag(&Ks[sb * 16 + qi][c * 32 + 8 * g]);
                acc = __builtin_amdgcn_mfma_f32_16x16x32_bf16(kf, qf[c], acc, 0, 0, 0);
            }
            st[sb] = acc;
        }
        // online softmax (q = qi is lane-local; reduce over g groups via xor16/32)
        float tmax = -INFINITY;
#pragma unroll
        for (int sb = 0; sb < 4; ++sb)
#pragma unroll
            for (int r = 0; r < 4; ++r) tmax = fmaxf(tmax, st[sb][r]);
        tmax = fmaxf(tmax, __shfl_xor(tmax, 16, 64));
        tmax = fmaxf(tmax, __shfl_xor(tmax, 32, 64));
        float mnew = fmaxf(m, tmax);
        float corr = __expf(m - mnew);
        m = mnew;
        float ps = 0.f;
#pragma unroll
        for (int sb = 0; sb < 4; ++sb) {
            float p0 = __expf(st[sb][0] - m);
            float p1 = __expf(st[sb][1] - m);
            float p2 = __expf(st[sb][2] - m);
            float p3 = __expf(st[sb][3] - m);
            ps += (p0 + p1) + (p2 + p3);
            uint2 w2; w2.x = pk(p0, p1); w2.y = pk(p2, p3);
            *(uint2*)&Pw[w][qi][sb * 16 + 4 * g] = w2;   // P[q][s], per-wave buffer
        }
        sum = sum * corr + ps;        // per-lane partial (this lane's s subset)
#pragma unroll
        for (int db = 0; db < 4; ++db) {
#pragma unroll
            for (int r = 0; r < 4; ++r) ot[db][r] *= corr;
        }
        // PV: O^T += V^T(d,s) * P^T(s,q)
#pragma unroll
        for (int db = 0; db < 4; ++db) {
#pragma unroll
            for (int sc = 0; sc < 2; ++sc) {
                short8 vf = ld_frag(&Vts[db * 16 + qi][sc * 32 + 8 * g]);
                short8 pf = ld_frag(&Pw[w][qi][sc * 32 + 8 * g]);
                ot[db] = __builtin_amdgcn_mfma_f32_16x16x32_bf16(vf, pf, ot[db], 0, 0, 0);
            }
        }
    }
    sum += __shfl_xor(sum, 16, 64);
    sum += __shfl_xor(sum, 32, 64);
    float rinv = 1.f / sum;
    // O^T lane layout: col q = qi, row d = db*16 + 4g + r
#pragma unroll
    for (int db = 0; db < 4; ++db) {
#pragma unroll
        for (int r = 0; r < 4; ++r) {
            int d = db * 16 + 4 * g + r;
            o[((size_t)(b * LL + q0 + qi)) * HDIM + h * DD + d] = ot[db][r] * rinv;
        }
    }
}

// ---------------- global-LN stats (2 stage) ----------------
__global__ __launch_bounds__(256) void k_stats1(const float* __restrict__ in,
                                                float* __restrict__ part) {
    int b = blockIdx.y;
    int chunk = blockIdx.x;
    const float4* p = (const float4*)(in + (size_t)b * CC * LL);
    int per = (CC * LL / 4) / NPART;
    float s = 0.f, s2 = 0.f;
    for (int i = chunk * per + threadIdx.x; i < (chunk + 1) * per; i += 256) {
        float4 vv = p[i];
        s  += vv.x + vv.y + vv.z + vv.w;
        s2 += vv.x * vv.x + vv.y * vv.y + vv.z * vv.z + vv.w * vv.w;
    }
    s = wred_sum(s); s2 = wred_sum(s2);
    __shared__ float rs[4], rs2[4];
    int wv = threadIdx.x >> 6;
    if ((threadIdx.x & 63) == 0) { rs[wv] = s; rs2[wv] = s2; }
    __syncthreads();
    if (threadIdx.x == 0) {
        part[(b * NPART + chunk) * 2 + 0] = rs[0] + rs[1] + rs[2] + rs[3];
        part[(b * NPART + chunk) * 2 + 1] = rs2[0] + rs2[1] + rs2[2] + rs2[3];
    }
}

__global__ __launch_bounds__(64) void k_stats2(const float* __restrict__ part,
                                               float* __restrict__ stats) {
    int b = blockIdx.x;
    int t = threadIdx.x;
    float s  = part[(b * NPART + t) * 2 + 0];
    float s2 = part[(b * NPART + t) * 2 + 1];
    s = wred_sum(s); s2 = wred_sum(s2);
    if (t == 0) {
        float mean = s / (float)(CC * LL);
        float var  = s2 / (float)(CC * LL) - mean * mean;
        stats[b * 2 + 0] = mean;
        stats[b * 2 + 1] = rsqrtf(var + EPSV);
    }
}

// ---------------- LN apply (+optional PReLU, +optional add, optional transpose-out) ----------------
__global__ __launch_bounds__(256) void k_ln(const float* in,
                                            const float* __restrict__ g,
                                            const float* __restrict__ be,
                                            const float* __restrict__ stats,
                                            const float* __restrict__ add,
                                            const float* __restrict__ alpha_ptr,
                                            float* out, int transpose_out) {
    int idx = blockIdx.x * 256 + threadIdx.x;
    int c = idx & (CC - 1);
    int b = idx / (CC * LL);
    float mean = stats[b * 2 + 0];
    float inv  = stats[b * 2 + 1];
    float vv = (in[idx] - mean) * inv * g[c] + be[c];
    if (alpha_ptr) {
        float al = alpha_ptr[0];
        vv = vv >= 0.f ? vv : al * vv;
    }
    if (add) vv += add[idx];
    if (transpose_out) {
        int l = (idx / CC) & (LL - 1);
        out[((size_t)b * CC + c) * LL + l] = vv;
    } else {
        out[idx] = vv;
    }
}

// ---------------- launch ----------------
extern "C" void kernel_launch(void* const* d_in, const int* in_sizes, int n_in,
                              void* d_out, int out_size, void* d_ws, size_t ws_size,
                              hipStream_t stream) {
    const float* x      = (const float*)d_in[0];
    const float* Wq     = (const float*)d_in[1];
    const float* bq     = (const float*)d_in[2];
    const float* Wk     = (const float*)d_in[3];
    const float* bk     = (const float*)d_in[4];
    const float* Wv     = (const float*)d_in[5];
    const float* bv     = (const float*)d_in[6];
    const float* Wo     = (const float*)d_in[7];
    const float* bo     = (const float*)d_in[8];
    const float* g_mha  = (const float*)d_in[9];
    const float* b_mha  = (const float*)d_in[10];
    const float* conv_w = (const float*)d_in[11];
    const float* conv_b = (const float*)d_in[12];
    const float* g_ffn  = (const float*)d_in[13];
    const float* b_ffn  = (const float*)d_in[14];
    const float* alpha  = (const float*)d_in[15];
    const float* g_out  = (const float*)d_in[16];
    const float* b_out  = (const float*)d_in[17];
    float* out = (float*)d_out;

    // workspace layout (float units)
    float* ws   = (float*)d_ws;
    float* t    = ws;                        // 1,048,576 f  (B,L,C)
    float* vbuf = ws + 1048576;              // 2,097,152 f  (B,L,HD) fp32 V
    unsigned short* Qbf = (unsigned short*)(ws + 3145728);   // 2M bf16 (1M f)
    unsigned short* Kbf = (unsigned short*)(ws + 4194304);   // 2M bf16
    unsigned short* Vt  = (unsigned short*)(ws + 5242880);   // 2M bf16
    float* obuf = ws + 6291456;              // 2,097,152 f  (B,L,HD)   [ends 8,388,608 f = 32MB]
    float* y    = ws + 3145728;              // reuse Qbf/Kbf region after attn
    float* f    = vbuf;                      // reuse vbuf after attn
    float* stats = ws + 5242880;             // reuse Vt region after attn
    float* parts = ws + 5242880 + 16;

    const int nelem = BB * LL * CC;
    const float scale = 0.125f;              // 1/sqrt(64)

    k_prep<<<nelem / 256, 256, 0, stream>>>(x, t);

    dim3 gqkv(BLQ / BM, HDIM / BN);
    k_gemm<<<gqkv, 256, 0, stream>>>(t, Wq, bq, nullptr, Qbf, 1, BLQ, HDIM, CC, scale);
    k_gemm<<<gqkv, 256, 0, stream>>>(t, Wk, bk, nullptr, Kbf, 1, BLQ, HDIM, CC, 1.f);
    k_gemm<<<gqkv, 256, 0, stream>>>(t, Wv, bv, nullptr, vbuf, 0, BLQ, HDIM, CC, 1.f);

    dim3 gvt(LL / 64, HH, BB);
    k_vtrans<<<gvt, 256, 0, stream>>>(vbuf, Vt);

    dim3 gattn(LL / 128, HH, BB);
    k_attn<<<gattn, 512, 0, stream>>>(Qbf, Kbf, Vt, obuf);

    dim3 gout(BLQ / BM, CC / BN);
    k_gemm<<<gout, 256, 0, stream>>>(obuf, Wo, bo, t, t, 0, BLQ, CC, HDIM, 1.f);

    dim3 gst(NPART, BB);
    k_stats1<<<gst, 256, 0, stream>>>(t, parts);
    k_stats2<<<BB, 64, 0, stream>>>(parts, stats);
    k_ln<<<nelem / 256, 256, 0, stream>>>(t, g_mha, b_mha, stats, nullptr, nullptr, y, 0);

    k_gemm<<<gout, 256, 0, stream>>>(y, conv_w, conv_b, nullptr, f, 0, BLQ, CC, CC, 1.f);

    k_stats1<<<gst, 256, 0, stream>>>(f, parts);
    k_stats2<<<BB, 64, 0, stream>>>(parts, stats + 4);
    k_ln<<<nelem / 256, 256, 0, stream>>>(f, g_ffn, b_ffn, stats + 4, y, alpha, f, 0);

    k_stats1<<<gst, 256, 0, stream>>>(f, parts);
    k_stats2<<<BB, 64, 0, stream>>>(parts, stats + 8);
    k_ln<<<nelem / 256, 256, 0, stream>>>(f, g_out, b_out, stats + 8, nullptr, nullptr, out, 1);
}

// Round 3
// 173.785 us; speedup vs baseline: 7.8701x; 1.1975x over previous
//
#include <hip/hip_runtime.h>
#include <hip/hip_bf16.h>
#include <math.h>

// Problem constants
#define BB   2
#define CC   256
#define LL   2048
#define DD   64
#define HH   8
#define HDIM 512
#define BLQ  (BB*LL)      // 4096 tokens
#define EPSV 1e-8f
#define NPART 64

typedef __attribute__((ext_vector_type(8))) short short8;   // 8 bf16 (4 VGPRs)
typedef __attribute__((ext_vector_type(4))) float f32x4;    // MFMA acc

// ---------------- helpers ----------------
__device__ __forceinline__ float wred_sum(float v) {
#pragma unroll
    for (int off = 32; off > 0; off >>= 1) v += __shfl_down(v, off, 64);
    return v;
}
// round-to-nearest-even fp32 -> bf16
__device__ __forceinline__ unsigned short f2bf(float x) {
    union { float f; unsigned u; } a; a.f = x;
    unsigned r = a.u + 0x7fff + ((a.u >> 16) & 1);
    return (unsigned short)(r >> 16);
}
__device__ __forceinline__ unsigned pk(float a, float b) {
    return (unsigned)f2bf(a) | ((unsigned)f2bf(b) << 16);
}

// ---------------- prep: t = x^T + PE (tiled transpose, dual fp32+bf16 out) ----------------
__global__ __launch_bounds__(256) void k_prep(const float* __restrict__ x,
                                              float* __restrict__ t,
                                              unsigned short* __restrict__ tb) {
    __shared__ float tr[64][65];    // [l][c]
    int l0 = blockIdx.x * 64, c0 = blockIdx.y * 64, b = blockIdx.z;
    int tid = threadIdx.x, r = tid >> 2, q = tid & 3;
#pragma unroll
    for (int p = 0; p < 4; ++p) {
        int lc = 4 * (q + 4 * p);
        float4 v = *(const float4*)&x[((size_t)(b * CC + c0 + r)) * LL + l0 + lc];
        tr[lc + 0][r] = v.x; tr[lc + 1][r] = v.y; tr[lc + 2][r] = v.z; tr[lc + 3][r] = v.w;
    }
    __syncthreads();
    int lg = l0 + r;
#pragma unroll
    for (int p = 0; p < 4; ++p) {
        int cc = 4 * (q + 4 * p);
        float4 v = *(const float4*)&tr[r][cc];
        float pe[4];
#pragma unroll
        for (int i = 0; i < 4; ++i) {
            int cg = c0 + cc + i;
            float freq = __expf((float)(cg & ~1) * (-9.210340371976184f / (float)CC));
            float ang = (float)lg * freq;
            pe[i] = (cg & 1) ? __cosf(ang) : __sinf(ang);
        }
        v.x += pe[0]; v.y += pe[1]; v.z += pe[2]; v.w += pe[3];
        size_t o = ((size_t)(b * LL + lg)) * CC + c0 + cc;
        *(float4*)&t[o] = v;
        uint2 u; u.x = pk(v.x, v.y); u.y = pk(v.z, v.w);
        *(uint2*)&tb[o] = u;
    }
}

// ---------------- weight convert fp32 -> bf16 (one launch) ----------------
// layout: Wqkv rows [0,512)=Wq, [512,1024)=Wk, [1024,1536)=Wv  (each [n][256])
__global__ __launch_bounds__(256) void k_cvtw(const float* __restrict__ Wq, const float* __restrict__ Wk,
                                              const float* __restrict__ Wv, const float* __restrict__ Wo,
                                              const float* __restrict__ Wc,
                                              unsigned short* __restrict__ dqkv,
                                              unsigned short* __restrict__ dWo,
                                              unsigned short* __restrict__ dWc) {
    int idx = (blockIdx.x * 256 + threadIdx.x) * 4;   // 589824 elements total
    const float* s; unsigned short* d;
    if (idx < 131072)      { s = Wq + idx;          d = dqkv + idx; }
    else if (idx < 262144) { s = Wk + idx - 131072; d = dqkv + idx; }
    else if (idx < 393216) { s = Wv + idx - 262144; d = dqkv + idx; }
    else if (idx < 524288) { s = Wo + idx - 393216; d = dWo + idx - 393216; }
    else                   { s = Wc + idx - 524288; d = dWc + idx - 524288; }
    float4 v = *(const float4*)s;
    uint2 u; u.x = pk(v.x, v.y); u.y = pk(v.z, v.w);
    *(uint2*)d = u;
}

// ---------------- MFMA GEMM: out = A @ W^T (+bias) (+resid) ----------------
// A: (M,K) bf16 row-major; W: (N,K) bf16 row-major.
// mode 0: fp32 out (M,N) += bias[n] (+resid, may alias out)
// mode 1: QKV. n<512 -> Q (x0.125), <1024 -> K, else V. Q/K stored (B,H,L,D) bf16;
//         V stored transposed (B,H,D,L) bf16 via swapped-operand MFMA.
#define MLDK 72
__global__ __launch_bounds__(256) void k_mm(const unsigned short* __restrict__ A,
                                            const unsigned short* __restrict__ W,
                                            const float* __restrict__ b0,
                                            const float* __restrict__ b1,
                                            const float* __restrict__ b2,
                                            const float* resid,
                                            float* out, unsigned short* outb,
                                            int mode, int M, int N, int K) {
    __shared__ __align__(16) unsigned short As[2][64][MLDK];
    __shared__ __align__(16) unsigned short Ws[2][64][MLDK];
    int tid = threadIdx.x;
    int w = tid >> 6, lane = tid & 63, g = lane >> 4, qi = lane & 15;
    int bm = blockIdx.x * 64, bn = blockIdx.y * 64;
    int wr = w >> 1, wc = w & 1;
    int srow = tid >> 2, sq = tid & 3;
    bool vseg = (mode == 1) && (bn >= 1024);
    f32x4 acc[2][2];
    acc[0][0] = acc[0][1] = acc[1][0] = acc[1][1] = (f32x4){0.f, 0.f, 0.f, 0.f};
    uint4 ra[2], rw[2];
#pragma unroll
    for (int p = 0; p < 2; ++p) {
        ra[p] = *(const uint4*)&A[(size_t)(bm + srow) * K + (sq + 4 * p) * 8];
        rw[p] = *(const uint4*)&W[(size_t)(bn + srow) * K + (sq + 4 * p) * 8];
    }
    int nt = K >> 6;
    for (int it = 0; it < nt; ++it) {
        int buf = it & 1;
#pragma unroll
        for (int p = 0; p < 2; ++p) {
            *(uint4*)&As[buf][srow][(sq + 4 * p) * 8] = ra[p];
            *(uint4*)&Ws[buf][srow][(sq + 4 * p) * 8] = rw[p];
        }
        __syncthreads();
        if (it + 1 < nt) {
            int k0 = (it + 1) << 6;
#pragma unroll
            for (int p = 0; p < 2; ++p) {
                ra[p] = *(const uint4*)&A[(size_t)(bm + srow) * K + k0 + (sq + 4 * p) * 8];
                rw[p] = *(const uint4*)&W[(size_t)(bn + srow) * K + k0 + (sq + 4 * p) * 8];
            }
        }
#pragma unroll
        for (int c = 0; c < 2; ++c) {
            short8 wf0 = *(const short8*)&Ws[buf][wr * 32 + 0  + qi][c * 32 + 8 * g];
            short8 wf1 = *(const short8*)&Ws[buf][wr * 32 + 16 + qi][c * 32 + 8 * g];
            short8 af0 = *(const short8*)&As[buf][wc * 32 + 0  + qi][c * 32 + 8 * g];
            short8 af1 = *(const short8*)&As[buf][wc * 32 + 16 + qi][c * 32 + 8 * g];
            if (!vseg) {
                acc[0][0] = __builtin_amdgcn_mfma_f32_16x16x32_bf16(wf0, af0, acc[0][0], 0, 0, 0);
                acc[0][1] = __builtin_amdgcn_mfma_f32_16x16x32_bf16(wf0, af1, acc[0][1], 0, 0, 0);
                acc[1][0] = __builtin_amdgcn_mfma_f32_16x16x32_bf16(wf1, af0, acc[1][0], 0, 0, 0);
                acc[1][1] = __builtin_amdgcn_mfma_f32_16x16x32_bf16(wf1, af1, acc[1][1], 0, 0, 0);
            } else {
                acc[0][0] = __builtin_amdgcn_mfma_f32_16x16x32_bf16(af0, wf0, acc[0][0], 0, 0, 0);
                acc[0][1] = __builtin_amdgcn_mfma_f32_16x16x32_bf16(af0, wf1, acc[0][1], 0, 0, 0);
                acc[1][0] = __builtin_amdgcn_mfma_f32_16x16x32_bf16(af1, wf0, acc[1][0], 0, 0, 0);
                acc[1][1] = __builtin_amdgcn_mfma_f32_16x16x32_bf16(af1, wf1, acc[1][1], 0, 0, 0);
            }
        }
    }
    if (mode == 0) {
#pragma unroll
        for (int fi = 0; fi < 2; ++fi)
#pragma unroll
            for (int fj = 0; fj < 2; ++fj) {
                int n0 = bn + wr * 32 + fi * 16 + 4 * g;
                int m  = bm + wc * 32 + fj * 16 + qi;
                float4 bi = *(const float4*)&b0[n0];
                float4 v;
                v.x = acc[fi][fj][0] + bi.x; v.y = acc[fi][fj][1] + bi.y;
                v.z = acc[fi][fj][2] + bi.z; v.w = acc[fi][fj][3] + bi.w;
                if (resid) {
                    float4 rv = *(const float4*)&resid[(size_t)m * N + n0];
                    v.x += rv.x; v.y += rv.y; v.z += rv.z; v.w += rv.w;
                }
                *(float4*)&out[(size_t)m * N + n0] = v;
            }
    } else if (!vseg) {
        int seg = bn >> 9;                      // 0 = Q, 1 = K
        const float* bs = seg ? b1 : b0;
        float sc = seg ? 1.f : 0.125f;          // 1/sqrt(64) folded into Q
#pragma unroll
        for (int fi = 0; fi < 2; ++fi)
#pragma unroll
            for (int fj = 0; fj < 2; ++fj) {
                int nn0 = (bn & 511) + wr * 32 + fi * 16 + 4 * g;
                int m   = bm + wc * 32 + fj * 16 + qi;
                int b = m >> 11, l = m & (LL - 1);
                int h = nn0 >> 6, d0 = nn0 & 63;
                float4 bi = *(const float4*)&bs[nn0];
                uint2 u;
                u.x = pk(sc * (acc[fi][fj][0] + bi.x), sc * (acc[fi][fj][1] + bi.y));
                u.y = pk(sc * (acc[fi][fj][2] + bi.z), sc * (acc[fi][fj][3] + bi.w));
                *(uint2*)&outb[(size_t)seg * 2097152 +
                               (((size_t)(b * HH + h)) * LL + l) * DD + d0] = u;
            }
    } else {
#pragma unroll
        for (int fi = 0; fi < 2; ++fi)
#pragma unroll
            for (int fj = 0; fj < 2; ++fj) {
                int m0 = bm + wc * 32 + fi * 16 + 4 * g;
                int nn = (bn & 511) + wr * 32 + fj * 16 + qi;
                int b = m0 >> 11, l0 = m0 & (LL - 1);
                int h = nn >> 6, d = nn & 63;
                float bi = b2[nn];
                uint2 u;
                u.x = pk(acc[fi][fj][0] + bi, acc[fi][fj][1] + bi);
                u.y = pk(acc[fi][fj][2] + bi, acc[fi][fj][3] + bi);
                *(uint2*)&outb[(size_t)2 * 2097152 +
                               (((size_t)(b * HH + h)) * DD + d) * LL + l0] = u;
            }
    }
}

// ---------------- MFMA flash attention ----------------
// QKV: seg0 Q (B,H,L,D), seg1 K (B,H,L,D), seg2 V^T (B,H,D,L), all bf16.
// 256 thr = 4 waves; wave w owns q rows [bx*64 + w*16, +16); K-tiles of 64, double-buffered.
#define LDK 72
__global__ __launch_bounds__(256) void k_attn(const unsigned short* __restrict__ QKV,
                                              unsigned short* __restrict__ o) {
    int h = blockIdx.y, b = blockIdx.z;
    int tid = threadIdx.x;
    int w = tid >> 6, lane = tid & 63, g = lane >> 4, qi = lane & 15;
    int q0 = blockIdx.x * 64 + w * 16;
    __shared__ __align__(16) unsigned short Ks[2][64][LDK];
    __shared__ __align__(16) unsigned short Vts[2][64][LDK];
    __shared__ __align__(16) unsigned short Pw[4][16][LDK];
    const size_t bh = (size_t)(b * HH + h);
    const unsigned short* Qg = QKV + bh * LL * DD;
    const unsigned short* Kg = QKV + 2097152 + bh * LL * DD;
    const unsigned short* Vg = QKV + 2 * 2097152 + bh * DD * LL;

    short8 qf[2];
#pragma unroll
    for (int c = 0; c < 2; ++c)
        qf[c] = *(const short8*)&Qg[(size_t)(q0 + qi) * DD + c * 32 + 8 * g];

    f32x4 ot[4];
#pragma unroll
    for (int db = 0; db < 4; ++db) ot[db] = (f32x4){0.f, 0.f, 0.f, 0.f};
    float m = -INFINITY, sum = 0.f;

    int srow = tid >> 2, sq = tid & 3;
    uint4 kr[2], vr[2];
#pragma unroll
    for (int p = 0; p < 2; ++p) {
        kr[p] = *(const uint4*)&Kg[(size_t)srow * DD + (sq + 4 * p) * 8];
        vr[p] = *(const uint4*)&Vg[(size_t)srow * LL + (sq + 4 * p) * 8];
    }
    for (int it = 0; it < LL / 64; ++it) {
        int buf = it & 1;
#pragma unroll
        for (int p = 0; p < 2; ++p) {
            *(uint4*)&Ks[buf][srow][(sq + 4 * p) * 8]  = kr[p];
            *(uint4*)&Vts[buf][srow][(sq + 4 * p) * 8] = vr[p];
        }
        __syncthreads();
        if (it + 1 < LL / 64) {
            int s1 = (it + 1) * 64;
#pragma unroll
            for (int p = 0; p < 2; ++p) {
                kr[p] = *(const uint4*)&Kg[(size_t)(s1 + srow) * DD + (sq + 4 * p) * 8];
                vr[p] = *(const uint4*)&Vg[(size_t)srow * LL + s1 + (sq + 4 * p) * 8];
            }
        }
        // S^T: lane holds (s = sb*16 + 4g + r, q = qi)
        f32x4 st[4];
#pragma unroll
        for (int sb = 0; sb < 4; ++sb) {
            f32x4 a = (f32x4){0.f, 0.f, 0.f, 0.f};
#pragma unroll
            for (int c = 0; c < 2; ++c) {
                short8 kf = *(const short8*)&Ks[buf][sb * 16 + qi][c * 32 + 8 * g];
                a = __builtin_amdgcn_mfma_f32_16x16x32_bf16(kf, qf[c], a, 0, 0, 0);
            }
            st[sb] = a;
        }
        float tmax = -INFINITY;
#pragma unroll
        for (int sb = 0; sb < 4; ++sb)
#pragma unroll
            for (int r = 0; r < 4; ++r) tmax = fmaxf(tmax, st[sb][r]);
        tmax = fmaxf(tmax, __shfl_xor(tmax, 16, 64));
        tmax = fmaxf(tmax, __shfl_xor(tmax, 32, 64));
        float mnew = fmaxf(m, tmax);
        float corr = __expf(m - mnew);
        m = mnew;
        float ps = 0.f;
#pragma unroll
        for (int sb = 0; sb < 4; ++sb) {
            float p0 = __expf(st[sb][0] - m);
            float p1 = __expf(st[sb][1] - m);
            float p2 = __expf(st[sb][2] - m);
            float p3 = __expf(st[sb][3] - m);
            ps += (p0 + p1) + (p2 + p3);
            uint2 w2; w2.x = pk(p0, p1); w2.y = pk(p2, p3);
            *(uint2*)&Pw[w][qi][sb * 16 + 4 * g] = w2;
        }
        sum = sum * corr + ps;
#pragma unroll
        for (int db = 0; db < 4; ++db)
#pragma unroll
            for (int r = 0; r < 4; ++r) ot[db][r] *= corr;
#pragma unroll
        for (int db = 0; db < 4; ++db)
#pragma unroll
            for (int sc = 0; sc < 2; ++sc) {
                short8 vf = *(const short8*)&Vts[buf][db * 16 + qi][sc * 32 + 8 * g];
                short8 pf = *(const short8*)&Pw[w][qi][sc * 32 + 8 * g];
                ot[db] = __builtin_amdgcn_mfma_f32_16x16x32_bf16(vf, pf, ot[db], 0, 0, 0);
            }
    }
    sum += __shfl_xor(sum, 16, 64);
    sum += __shfl_xor(sum, 32, 64);
    float rinv = 1.f / sum;
#pragma unroll
    for (int db = 0; db < 4; ++db) {
        int d0 = db * 16 + 4 * g;
        uint2 u;
        u.x = pk(ot[db][0] * rinv, ot[db][1] * rinv);
        u.y = pk(ot[db][2] * rinv, ot[db][3] * rinv);
        *(uint2*)&o[((size_t)(b * LL + q0 + qi)) * HDIM + h * DD + d0] = u;
    }
}

// ---------------- global-LN stats (2 stage) ----------------
__global__ __launch_bounds__(256) void k_stats1(const float* __restrict__ in,
                                                float* __restrict__ part) {
    int b = blockIdx.y, chunk = blockIdx.x;
    const float4* p = (const float4*)(in + (size_t)b * CC * LL);
    int per = (CC * LL / 4) / NPART;
    float s = 0.f, s2 = 0.f;
    for (int i = chunk * per + threadIdx.x; i < (chunk + 1) * per; i += 256) {
        float4 vv = p[i];
        s  += vv.x + vv.y + vv.z + vv.w;
        s2 += vv.x * vv.x + vv.y * vv.y + vv.z * vv.z + vv.w * vv.w;
    }
    s = wred_sum(s); s2 = wred_sum(s2);
    __shared__ float rs[4], rs2[4];
    int wv = threadIdx.x >> 6;
    if ((threadIdx.x & 63) == 0) { rs[wv] = s; rs2[wv] = s2; }
    __syncthreads();
    if (threadIdx.x == 0) {
        part[(b * NPART + chunk) * 2 + 0] = rs[0] + rs[1] + rs[2] + rs[3];
        part[(b * NPART + chunk) * 2 + 1] = rs2[0] + rs2[1] + rs2[2] + rs2[3];
    }
}

__global__ __launch_bounds__(64) void k_stats2(const float* __restrict__ part,
                                               float* __restrict__ stats) {
    int b = blockIdx.x, t = threadIdx.x;
    float s  = part[(b * NPART + t) * 2 + 0];
    float s2 = part[(b * NPART + t) * 2 + 1];
    s = wred_sum(s); s2 = wred_sum(s2);
    if (t == 0) {
        float mean = s / (float)(CC * LL);
        float var  = s2 / (float)(CC * LL) - mean * mean;
        stats[b * 2 + 0] = mean;
        stats[b * 2 + 1] = rsqrtf(var + EPSV);
    }
}

// ---------------- LN apply, vectorized (+PReLU, +add, +bf16 copy) ----------------
__global__ __launch_bounds__(256) void k_ln(const float* in,
                                            const float* __restrict__ g,
                                            const float* __restrict__ be,
                                            const float* __restrict__ stats,
                                            const float* __restrict__ add,
                                            const float* __restrict__ alpha_ptr,
                                            float* out, unsigned short* outb) {
    int idx = (blockIdx.x * 256 + threadIdx.x) * 4;
    int c = idx & (CC - 1);
    int b = idx / (CC * LL);
    float mean = stats[b * 2 + 0], inv = stats[b * 2 + 1];
    float4 v  = *(const float4*)&in[idx];
    float4 gg = *(const float4*)&g[c];
    float4 bb = *(const float4*)&be[c];
    v.x = (v.x - mean) * inv * gg.x + bb.x;
    v.y = (v.y - mean) * inv * gg.y + bb.y;
    v.z = (v.z - mean) * inv * gg.z + bb.z;
    v.w = (v.w - mean) * inv * gg.w + bb.w;
    if (alpha_ptr) {
        float al = alpha_ptr[0];
        v.x = v.x >= 0.f ? v.x : al * v.x;
        v.y = v.y >= 0.f ? v.y : al * v.y;
        v.z = v.z >= 0.f ? v.z : al * v.z;
        v.w = v.w >= 0.f ? v.w : al * v.w;
    }
    if (add) {
        float4 a = *(const float4*)&add[idx];
        v.x += a.x; v.y += a.y; v.z += a.z; v.w += a.w;
    }
    *(float4*)&out[idx] = v;
    if (outb) {
        uint2 u; u.x = pk(v.x, v.y); u.y = pk(v.z, v.w);
        *(uint2*)&outb[idx] = u;
    }
}

// ---------------- final LN + transpose out (B,L,C) -> (B,C,L) ----------------
__global__ __launch_bounds__(256) void k_ln_t(const float* __restrict__ in,
                                              const float* __restrict__ g,
                                              const float* __restrict__ be,
                                              const float* __restrict__ stats,
                                              float* __restrict__ out) {
    __shared__ float tr[64][65];   // [c][l]
    int l0 = blockIdx.x * 64, c0 = blockIdx.y * 64, b = blockIdx.z;
    int tid = threadIdx.x, r = tid >> 2, q = tid & 3;
    float mean = stats[b * 2 + 0], inv = stats[b * 2 + 1];
#pragma unroll
    for (int p = 0; p < 4; ++p) {
        int cc = 4 * (q + 4 * p);
        float4 v  = *(const float4*)&in[((size_t)(b * LL + l0 + r)) * CC + c0 + cc];
        float4 gg = *(const float4*)&g[c0 + cc];
        float4 bb = *(const float4*)&be[c0 + cc];
        tr[cc + 0][r] = (v.x - mean) * inv * gg.x + bb.x;
        tr[cc + 1][r] = (v.y - mean) * inv * gg.y + bb.y;
        tr[cc + 2][r] = (v.z - mean) * inv * gg.z + bb.z;
        tr[cc + 3][r] = (v.w - mean) * inv * gg.w + bb.w;
    }
    __syncthreads();
#pragma unroll
    for (int p = 0; p < 4; ++p) {
        int ll = 4 * (q + 4 * p);
        float4 v = *(const float4*)&tr[r][ll];
        *(float4*)&out[((size_t)(b * CC + c0 + r)) * LL + l0 + ll] = v;
    }
}

// ---------------- launch ----------------
extern "C" void kernel_launch(void* const* d_in, const int* in_sizes, int n_in,
                              void* d_out, int out_size, void* d_ws, size_t ws_size,
                              hipStream_t stream) {
    const float* x      = (const float*)d_in[0];
    const float* Wq     = (const float*)d_in[1];
    const float* bq     = (const float*)d_in[2];
    const float* Wk     = (const float*)d_in[3];
    const float* bk     = (const float*)d_in[4];
    const float* Wv     = (const float*)d_in[5];
    const float* bv     = (const float*)d_in[6];
    const float* Wo     = (const float*)d_in[7];
    const float* bo     = (const float*)d_in[8];
    const float* g_mha  = (const float*)d_in[9];
    const float* b_mha  = (const float*)d_in[10];
    const float* conv_w = (const float*)d_in[11];
    const float* conv_b = (const float*)d_in[12];
    const float* g_ffn  = (const float*)d_in[13];
    const float* b_ffn  = (const float*)d_in[14];
    const float* alpha  = (const float*)d_in[15];
    const float* g_out  = (const float*)d_in[16];
    const float* b_out  = (const float*)d_in[17];
    float* out = (float*)d_out;

    // workspace layout (float units)
    float* ws = (float*)d_ws;
    float* t            = ws;                                      // 1M f   (B,L,C); becomes y in-place
    unsigned short* tb  = (unsigned short*)(ws + 1048576);         // 2M bf16
    unsigned short* QKVb= (unsigned short*)(ws + 1572864);         // 3 x 2M bf16 (Q,K,V^T)
    float* f            = ws + 1572864;                            // 1M f, reuses QKV after attn
    unsigned short* obuf= (unsigned short*)(ws + 4572864);         // 2M bf16
    unsigned short* Wqkvb=(unsigned short*)(ws + 5572864);         // 393216 bf16
    unsigned short* Wob = (unsigned short*)(ws + 5769472);         // 131072 bf16
    unsigned short* Wcb = (unsigned short*)(ws + 5835008);         // 65536 bf16
    float* stats        = ws + 5867776;                            // 16
    float* parts        = ws + 5867792;                            // 256
    unsigned short* ybf = (unsigned short*)(ws + 5868064);         // 2M bf16

    dim3 gtile(LL / 64, CC / 64, BB);        // 32,4,2
    k_prep<<<gtile, 256, 0, stream>>>(x, t, tb);
    k_cvtw<<<576, 256, 0, stream>>>(Wq, Wk, Wv, Wo, conv_w, Wqkvb, Wob, Wcb);

    dim3 gqkv(BLQ / 64, 1536 / 64);          // 64,24
    k_mm<<<gqkv, 256, 0, stream>>>(tb, Wqkvb, bq, bk, bv, nullptr, nullptr, QKVb,
                                   1, BLQ, 1536, CC);

    dim3 gattn(LL / 64, HH, BB);             // 32,8,2
    k_attn<<<gattn, 256, 0, stream>>>(QKVb, obuf);

    dim3 go(BLQ / 64, CC / 64);              // 64,4
    k_mm<<<go, 256, 0, stream>>>(obuf, Wob, bo, nullptr, nullptr, t, t, nullptr,
                                 0, BLQ, CC, HDIM);                // t += o@Wo^T+bo

    dim3 gst(NPART, BB);
    k_stats1<<<gst, 256, 0, stream>>>(t, parts);
    k_stats2<<<BB, 64, 0, stream>>>(parts, stats);
    k_ln<<<1024, 256, 0, stream>>>(t, g_mha, b_mha, stats, nullptr, nullptr, t, ybf); // y := ln(t)

    k_mm<<<go, 256, 0, stream>>>(ybf, Wcb, conv_b, nullptr, nullptr, nullptr, f, nullptr,
                                 0, BLQ, CC, CC);

    k_stats1<<<gst, 256, 0, stream>>>(f, parts);
    k_stats2<<<BB, 64, 0, stream>>>(parts, stats + 4);
    k_ln<<<1024, 256, 0, stream>>>(f, g_ffn, b_ffn, stats + 4, t, alpha, f, nullptr);

    k_stats1<<<gst, 256, 0, stream>>>(f, parts);
    k_stats2<<<BB, 64, 0, stream>>>(parts, stats + 8);
    k_ln_t<<<gtile, 256, 0, stream>>>(f, g_out, b_out, stats + 8, out);
}

// Round 4
// 95.412 us; speedup vs baseline: 14.3346x; 1.8214x over previous
//
#include <hip/hip_runtime.h>
#include <hip/hip_bf16.h>
#include <math.h>

// Problem constants
#define BB   2
#define CC   256
#define LL   2048
#define DD   64
#define HH   8
#define HDIM 512
#define BLQ  (BB*LL)      // 4096 tokens
#define EPSV 1e-8f

typedef __attribute__((ext_vector_type(8))) short short8;   // 8 bf16 (4 VGPRs)
typedef __attribute__((ext_vector_type(4))) float f32x4;    // MFMA acc

// ---------------- helpers ----------------
__device__ __forceinline__ float wred_sum(float v) {
#pragma unroll
    for (int off = 32; off > 0; off >>= 1) v += __shfl_down(v, off, 64);
    return v;
}
// round-to-nearest-even fp32 -> bf16
__device__ __forceinline__ unsigned short f2bf(float x) {
    union { float f; unsigned u; } a; a.f = x;
    unsigned r = a.u + 0x7fff + ((a.u >> 16) & 1);
    return (unsigned short)(r >> 16);
}
__device__ __forceinline__ unsigned pk(float a, float b) {
    return (unsigned)f2bf(a) | ((unsigned)f2bf(b) << 16);
}
// assemble a bf16x8 fragment from two 8B LDS loads (zero-conflict pattern, round 2)
__device__ __forceinline__ short8 ld_frag(const unsigned short* p) {
    union { short8 v; uint2 u[2]; } f;
    f.u[0] = *(const uint2*)p;
    f.u[1] = *(const uint2*)(p + 4);
    return f.v;
}

// ---------------- prep: t = x^T + PE (tiled transpose, dual fp32+bf16 out) ----------------
__global__ __launch_bounds__(256) void k_prep(const float* __restrict__ x,
                                              float* __restrict__ t,
                                              unsigned short* __restrict__ tb) {
    __shared__ float tr[64][65];    // [l][c]
    int l0 = blockIdx.x * 64, c0 = blockIdx.y * 64, b = blockIdx.z;
    int tid = threadIdx.x, r = tid >> 2, q = tid & 3;
#pragma unroll
    for (int p = 0; p < 4; ++p) {
        int lc = 4 * (q + 4 * p);
        float4 v = *(const float4*)&x[((size_t)(b * CC + c0 + r)) * LL + l0 + lc];
        tr[lc + 0][r] = v.x; tr[lc + 1][r] = v.y; tr[lc + 2][r] = v.z; tr[lc + 3][r] = v.w;
    }
    __syncthreads();
    int lg = l0 + r;
#pragma unroll
    for (int p = 0; p < 4; ++p) {
        int cc = 4 * (q + 4 * p);
        float4 v = *(const float4*)&tr[r][cc];
        float pe[4];
#pragma unroll
        for (int i = 0; i < 4; ++i) {
            int cg = c0 + cc + i;
            float freq = __expf((float)(cg & ~1) * (-9.210340371976184f / (float)CC));
            float ang = (float)lg * freq;
            pe[i] = (cg & 1) ? __cosf(ang) : __sinf(ang);
        }
        v.x += pe[0]; v.y += pe[1]; v.z += pe[2]; v.w += pe[3];
        size_t o = ((size_t)(b * LL + lg)) * CC + c0 + cc;
        *(float4*)&t[o] = v;
        uint2 u; u.x = pk(v.x, v.y); u.y = pk(v.z, v.w);
        *(uint2*)&tb[o] = u;
    }
}

// ---------------- weight convert fp32 -> bf16 (one launch) ----------------
__global__ __launch_bounds__(256) void k_cvtw(const float* __restrict__ Wq, const float* __restrict__ Wk,
                                              const float* __restrict__ Wv, const float* __restrict__ Wo,
                                              const float* __restrict__ Wc,
                                              unsigned short* __restrict__ dqkv,
                                              unsigned short* __restrict__ dWo,
                                              unsigned short* __restrict__ dWc) {
    int idx = (blockIdx.x * 256 + threadIdx.x) * 4;   // 589824 elements total
    const float* s; unsigned short* d;
    if (idx < 131072)      { s = Wq + idx;          d = dqkv + idx; }
    else if (idx < 262144) { s = Wk + idx - 131072; d = dqkv + idx; }
    else if (idx < 393216) { s = Wv + idx - 262144; d = dqkv + idx; }
    else if (idx < 524288) { s = Wo + idx - 393216; d = dWo + idx - 393216; }
    else                   { s = Wc + idx - 524288; d = dWc + idx - 524288; }
    float4 v = *(const float4*)s;
    uint2 u; u.x = pk(v.x, v.y); u.y = pk(v.z, v.w);
    *(uint2*)d = u;
}

// ---------------- MFMA GEMM: out = A @ W^T (+bias) (+resid) (+partial LN stats) --------
// A: (M,K) bf16 row-major; W: (N,K) bf16 row-major.
// mode 0: fp32 out (M,N) += bias[n] (+resid, may alias out); pstat: per-block {sum,sumsq}
// mode 1: QKV. n<512 -> Q (x0.125), <1024 -> K, else V. Q/K stored (B,H,L,D) bf16;
//         V stored transposed (B,H,D,L) bf16 via swapped-operand MFMA.
#define MLDK 68
__global__ __launch_bounds__(256) void k_mm(const unsigned short* __restrict__ A,
                                            const unsigned short* __restrict__ W,
                                            const float* __restrict__ b0,
                                            const float* __restrict__ b1,
                                            const float* __restrict__ b2,
                                            const float* resid,
                                            float* out, unsigned short* outb,
                                            float* pstat,
                                            int mode, int M, int N, int K) {
    __shared__ unsigned short As[2][64][MLDK];
    __shared__ unsigned short Ws[2][64][MLDK];
    __shared__ float rs[4][2];
    int tid = threadIdx.x;
    int w = tid >> 6, lane = tid & 63, g = lane >> 4, qi = lane & 15;
    int bm = blockIdx.x * 64, bn = blockIdx.y * 64;
    int wr = w >> 1, wc = w & 1;
    int srow = tid >> 2, sq = tid & 3;
    bool vseg = (mode == 1) && (bn >= 1024);
    f32x4 acc[2][2];
    acc[0][0] = acc[0][1] = acc[1][0] = acc[1][1] = (f32x4){0.f, 0.f, 0.f, 0.f};
    uint4 ra[2], rw[2];
#pragma unroll
    for (int p = 0; p < 2; ++p) {
        ra[p] = *(const uint4*)&A[(size_t)(bm + srow) * K + (sq + 4 * p) * 8];
        rw[p] = *(const uint4*)&W[(size_t)(bn + srow) * K + (sq + 4 * p) * 8];
    }
    int nt = K >> 6;
    for (int it = 0; it < nt; ++it) {
        int buf = it & 1;
#pragma unroll
        for (int p = 0; p < 2; ++p) {
            *(uint2*)&As[buf][srow][(sq + 4 * p) * 8]     = make_uint2(ra[p].x, ra[p].y);
            *(uint2*)&As[buf][srow][(sq + 4 * p) * 8 + 4] = make_uint2(ra[p].z, ra[p].w);
            *(uint2*)&Ws[buf][srow][(sq + 4 * p) * 8]     = make_uint2(rw[p].x, rw[p].y);
            *(uint2*)&Ws[buf][srow][(sq + 4 * p) * 8 + 4] = make_uint2(rw[p].z, rw[p].w);
        }
        __syncthreads();
        if (it + 1 < nt) {
            int k0 = (it + 1) << 6;
#pragma unroll
            for (int p = 0; p < 2; ++p) {
                ra[p] = *(const uint4*)&A[(size_t)(bm + srow) * K + k0 + (sq + 4 * p) * 8];
                rw[p] = *(const uint4*)&W[(size_t)(bn + srow) * K + k0 + (sq + 4 * p) * 8];
            }
        }
#pragma unroll
        for (int c = 0; c < 2; ++c) {
            short8 wf0 = ld_frag(&Ws[buf][wr * 32 + 0  + qi][c * 32 + 8 * g]);
            short8 wf1 = ld_frag(&Ws[buf][wr * 32 + 16 + qi][c * 32 + 8 * g]);
            short8 af0 = ld_frag(&As[buf][wc * 32 + 0  + qi][c * 32 + 8 * g]);
            short8 af1 = ld_frag(&As[buf][wc * 32 + 16 + qi][c * 32 + 8 * g]);
            if (!vseg) {
                acc[0][0] = __builtin_amdgcn_mfma_f32_16x16x32_bf16(wf0, af0, acc[0][0], 0, 0, 0);
                acc[0][1] = __builtin_amdgcn_mfma_f32_16x16x32_bf16(wf0, af1, acc[0][1], 0, 0, 0);
                acc[1][0] = __builtin_amdgcn_mfma_f32_16x16x32_bf16(wf1, af0, acc[1][0], 0, 0, 0);
                acc[1][1] = __builtin_amdgcn_mfma_f32_16x16x32_bf16(wf1, af1, acc[1][1], 0, 0, 0);
            } else {
                acc[0][0] = __builtin_amdgcn_mfma_f32_16x16x32_bf16(af0, wf0, acc[0][0], 0, 0, 0);
                acc[0][1] = __builtin_amdgcn_mfma_f32_16x16x32_bf16(af0, wf1, acc[0][1], 0, 0, 0);
                acc[1][0] = __builtin_amdgcn_mfma_f32_16x16x32_bf16(af1, wf0, acc[1][0], 0, 0, 0);
                acc[1][1] = __builtin_amdgcn_mfma_f32_16x16x32_bf16(af1, wf1, acc[1][1], 0, 0, 0);
            }
        }
    }
    if (mode == 0) {
        float s = 0.f, s2 = 0.f;
#pragma unroll
        for (int fi = 0; fi < 2; ++fi)
#pragma unroll
            for (int fj = 0; fj < 2; ++fj) {
                int n0 = bn + wr * 32 + fi * 16 + 4 * g;
                int m  = bm + wc * 32 + fj * 16 + qi;
                float4 bi = *(const float4*)&b0[n0];
                float4 v;
                v.x = acc[fi][fj][0] + bi.x; v.y = acc[fi][fj][1] + bi.y;
                v.z = acc[fi][fj][2] + bi.z; v.w = acc[fi][fj][3] + bi.w;
                if (resid) {
                    float4 rv = *(const float4*)&resid[(size_t)m * N + n0];
                    v.x += rv.x; v.y += rv.y; v.z += rv.z; v.w += rv.w;
                }
                *(float4*)&out[(size_t)m * N + n0] = v;
                s  += (v.x + v.y) + (v.z + v.w);
                s2 += v.x * v.x + v.y * v.y + v.z * v.z + v.w * v.w;
            }
        if (pstat) {
            s = wred_sum(s); s2 = wred_sum(s2);
            if (lane == 0) { rs[w][0] = s; rs[w][1] = s2; }
            __syncthreads();
            if (tid == 0) {
                int bid = blockIdx.y * gridDim.x + blockIdx.x;
                pstat[bid * 2 + 0] = rs[0][0] + rs[1][0] + rs[2][0] + rs[3][0];
                pstat[bid * 2 + 1] = rs[0][1] + rs[1][1] + rs[2][1] + rs[3][1];
            }
        }
    } else if (!vseg) {
        int seg = bn >> 9;                      // 0 = Q, 1 = K
        const float* bs = seg ? b1 : b0;
        float sc = seg ? 1.f : 0.125f;          // 1/sqrt(64) folded into Q
#pragma unroll
        for (int fi = 0; fi < 2; ++fi)
#pragma unroll
            for (int fj = 0; fj < 2; ++fj) {
                int nn0 = (bn & 511) + wr * 32 + fi * 16 + 4 * g;
                int m   = bm + wc * 32 + fj * 16 + qi;
                int b = m >> 11, l = m & (LL - 1);
                int h = nn0 >> 6, d0 = nn0 & 63;
                float4 bi = *(const float4*)&bs[nn0];
                uint2 u;
                u.x = pk(sc * (acc[fi][fj][0] + bi.x), sc * (acc[fi][fj][1] + bi.y));
                u.y = pk(sc * (acc[fi][fj][2] + bi.z), sc * (acc[fi][fj][3] + bi.w));
                *(uint2*)&outb[(size_t)seg * 2097152 +
                               (((size_t)(b * HH + h)) * LL + l) * DD + d0] = u;
            }
    } else {
#pragma unroll
        for (int fi = 0; fi < 2; ++fi)
#pragma unroll
            for (int fj = 0; fj < 2; ++fj) {
                int m0 = bm + wc * 32 + fi * 16 + 4 * g;
                int nn = (bn & 511) + wr * 32 + fj * 16 + qi;
                int b = m0 >> 11, l0 = m0 & (LL - 1);
                int h = nn >> 6, d = nn & 63;
                float bi = b2[nn];
                uint2 u;
                u.x = pk(acc[fi][fj][0] + bi, acc[fi][fj][1] + bi);
                u.y = pk(acc[fi][fj][2] + bi, acc[fi][fj][3] + bi);
                *(uint2*)&outb[(size_t)2 * 2097152 +
                               (((size_t)(b * HH + h)) * DD + d) * LL + l0] = u;
            }
    }
}

// ---------------- MFMA flash attention ----------------
// QKV: seg0 Q (B,H,L,D), seg1 K (B,H,L,D), seg2 V^T (B,H,D,L), all bf16.
// 256 thr = 4 waves; wave w owns q rows [bx*64 + w*16, +16); K-tiles of 64, double-buffered.
// LDS: b64 accesses at stride 68 (136B) — measured-zero-conflict pattern (round 2).
#define LDK 68
__global__ __launch_bounds__(256) void k_attn(const unsigned short* __restrict__ QKV,
                                              unsigned short* __restrict__ o) {
    int h = blockIdx.y, b = blockIdx.z;
    int tid = threadIdx.x;
    int w = tid >> 6, lane = tid & 63, g = lane >> 4, qi = lane & 15;
    int q0 = blockIdx.x * 64 + w * 16;
    __shared__ unsigned short Ks[2][64][LDK];
    __shared__ unsigned short Vts[2][64][LDK];
    __shared__ unsigned short Pw[4][16][LDK];
    const size_t bh = (size_t)(b * HH + h);
    const unsigned short* Qg = QKV + bh * LL * DD;
    const unsigned short* Kg = QKV + 2097152 + bh * LL * DD;
    const unsigned short* Vg = QKV + (size_t)2 * 2097152 + bh * DD * LL;

    short8 qf[2];
#pragma unroll
    for (int c = 0; c < 2; ++c)
        qf[c] = *(const short8*)&Qg[(size_t)(q0 + qi) * DD + c * 32 + 8 * g];

    f32x4 ot[4];
#pragma unroll
    for (int db = 0; db < 4; ++db) ot[db] = (f32x4){0.f, 0.f, 0.f, 0.f};
    float m = -INFINITY, sum = 0.f;

    int srow = tid >> 2, sq = tid & 3;
    uint4 kr[2], vr[2];
#pragma unroll
    for (int p = 0; p < 2; ++p) {
        kr[p] = *(const uint4*)&Kg[(size_t)srow * DD + (sq + 4 * p) * 8];
        vr[p] = *(const uint4*)&Vg[(size_t)srow * LL + (sq + 4 * p) * 8];
    }
    for (int it = 0; it < LL / 64; ++it) {
        int buf = it & 1;
#pragma unroll
        for (int p = 0; p < 2; ++p) {
            *(uint2*)&Ks[buf][srow][(sq + 4 * p) * 8]      = make_uint2(kr[p].x, kr[p].y);
            *(uint2*)&Ks[buf][srow][(sq + 4 * p) * 8 + 4]  = make_uint2(kr[p].z, kr[p].w);
            *(uint2*)&Vts[buf][srow][(sq + 4 * p) * 8]     = make_uint2(vr[p].x, vr[p].y);
            *(uint2*)&Vts[buf][srow][(sq + 4 * p) * 8 + 4] = make_uint2(vr[p].z, vr[p].w);
        }
        __syncthreads();
        if (it + 1 < LL / 64) {
            int s1 = (it + 1) * 64;
#pragma unroll
            for (int p = 0; p < 2; ++p) {
                kr[p] = *(const uint4*)&Kg[(size_t)(s1 + srow) * DD + (sq + 4 * p) * 8];
                vr[p] = *(const uint4*)&Vg[(size_t)srow * LL + s1 + (sq + 4 * p) * 8];
            }
        }
        // S^T: lane holds (s = sb*16 + 4g + r, q = qi)
        f32x4 st[4];
        __builtin_amdgcn_s_setprio(1);
#pragma unroll
        for (int sb = 0; sb < 4; ++sb) {
            f32x4 a = (f32x4){0.f, 0.f, 0.f, 0.f};
#pragma unroll
            for (int c = 0; c < 2; ++c) {
                short8 kf = ld_frag(&Ks[buf][sb * 16 + qi][c * 32 + 8 * g]);
                a = __builtin_amdgcn_mfma_f32_16x16x32_bf16(kf, qf[c], a, 0, 0, 0);
            }
            st[sb] = a;
        }
        __builtin_amdgcn_s_setprio(0);
        // per-q (lane-local) tile max across the 4 g-groups
        float tmax = -INFINITY;
#pragma unroll
        for (int sb = 0; sb < 4; ++sb)
#pragma unroll
            for (int r = 0; r < 4; ++r) tmax = fmaxf(tmax, st[sb][r]);
        tmax = fmaxf(tmax, __shfl_xor(tmax, 16, 64));
        tmax = fmaxf(tmax, __shfl_xor(tmax, 32, 64));
        // T13 defer-max: only rescale when the running max grew materially
        if (!__all(tmax - m <= 8.f)) {
            float mnew = fmaxf(m, tmax);
            float corr = __expf(m - mnew);
            m = mnew;
            sum *= corr;
#pragma unroll
            for (int db = 0; db < 4; ++db)
#pragma unroll
                for (int r = 0; r < 4; ++r) ot[db][r] *= corr;
        }
        float ps = 0.f;
#pragma unroll
        for (int sb = 0; sb < 4; ++sb) {
            float p0 = __expf(st[sb][0] - m);
            float p1 = __expf(st[sb][1] - m);
            float p2 = __expf(st[sb][2] - m);
            float p3 = __expf(st[sb][3] - m);
            ps += (p0 + p1) + (p2 + p3);
            uint2 w2; w2.x = pk(p0, p1); w2.y = pk(p2, p3);
            *(uint2*)&Pw[w][qi][sb * 16 + 4 * g] = w2;
        }
        sum += ps;
        // PV: O^T += V^T(d,s) * P^T(s,q)
        __builtin_amdgcn_s_setprio(1);
#pragma unroll
        for (int db = 0; db < 4; ++db)
#pragma unroll
            for (int sc = 0; sc < 2; ++sc) {
                short8 vf = ld_frag(&Vts[buf][db * 16 + qi][sc * 32 + 8 * g]);
                short8 pf = ld_frag(&Pw[w][qi][sc * 32 + 8 * g]);
                ot[db] = __builtin_amdgcn_mfma_f32_16x16x32_bf16(vf, pf, ot[db], 0, 0, 0);
            }
        __builtin_amdgcn_s_setprio(0);
    }
    sum += __shfl_xor(sum, 16, 64);
    sum += __shfl_xor(sum, 32, 64);
    float rinv = 1.f / sum;
#pragma unroll
    for (int db = 0; db < 4; ++db) {
        int d0 = db * 16 + 4 * g;
        uint2 u;
        u.x = pk(ot[db][0] * rinv, ot[db][1] * rinv);
        u.y = pk(ot[db][2] * rinv, ot[db][3] * rinv);
        *(uint2*)&o[((size_t)(b * LL + q0 + qi)) * HDIM + h * DD + d0] = u;
    }
}

// ---------------- LN apply, vectorized (+PReLU, +add, +bf16 copy, +out partials) ------
// Consumes producer partials in GEMM-grid layout (gridDim.x=64: pidx = by*64 + bx,
// batch b owns bx in [b*32, b*32+32), by 0..3 -> 128 entries).
__global__ __launch_bounds__(256) void k_ln(const float* in,
                                            const float* __restrict__ g,
                                            const float* __restrict__ be,
                                            const float* __restrict__ pin,
                                            const float* __restrict__ add,
                                            const float* __restrict__ alpha_ptr,
                                            float* out, unsigned short* outb,
                                            float* pout) {
    __shared__ float rs[4][2];
    int tid = threadIdx.x;
    int b = blockIdx.x >> 9;           // 512 blocks per batch
    float s = 0.f, s2 = 0.f;
    if (tid < 128) {
        int pidx = (tid >> 5) * 64 + b * 32 + (tid & 31);
        s  = pin[pidx * 2 + 0];
        s2 = pin[pidx * 2 + 1];
    }
    s = wred_sum(s); s2 = wred_sum(s2);
    if ((tid & 63) == 0 && tid < 128) { rs[tid >> 6][0] = s; rs[tid >> 6][1] = s2; }
    __syncthreads();
    float S = rs[0][0] + rs[1][0], S2 = rs[0][1] + rs[1][1];
    float mean = S / (float)(CC * LL);
    float inv  = rsqrtf(S2 / (float)(CC * LL) - mean * mean + EPSV);

    int idx = (blockIdx.x * 256 + tid) * 4;
    int c = idx & (CC - 1);
    float4 v  = *(const float4*)&in[idx];
    float4 gg = *(const float4*)&g[c];
    float4 bb = *(const float4*)&be[c];
    v.x = (v.x - mean) * inv * gg.x + bb.x;
    v.y = (v.y - mean) * inv * gg.y + bb.y;
    v.z = (v.z - mean) * inv * gg.z + bb.z;
    v.w = (v.w - mean) * inv * gg.w + bb.w;
    if (alpha_ptr) {
        float al = alpha_ptr[0];
        v.x = v.x >= 0.f ? v.x : al * v.x;
        v.y = v.y >= 0.f ? v.y : al * v.y;
        v.z = v.z >= 0.f ? v.z : al * v.z;
        v.w = v.w >= 0.f ? v.w : al * v.w;
    }
    if (add) {
        float4 a = *(const float4*)&add[idx];
        v.x += a.x; v.y += a.y; v.z += a.z; v.w += a.w;
    }
    *(float4*)&out[idx] = v;
    if (outb) {
        uint2 u; u.x = pk(v.x, v.y); u.y = pk(v.z, v.w);
        *(uint2*)&outb[idx] = u;
    }
    if (pout) {
        float os  = (v.x + v.y) + (v.z + v.w);
        float os2 = v.x * v.x + v.y * v.y + v.z * v.z + v.w * v.w;
        os = wred_sum(os); os2 = wred_sum(os2);
        __syncthreads();   // rs reuse
        if ((tid & 63) == 0) { rs[tid >> 6][0] = os; rs[tid >> 6][1] = os2; }
        __syncthreads();
        if (tid == 0) {
            pout[blockIdx.x * 2 + 0] = rs[0][0] + rs[1][0] + rs[2][0] + rs[3][0];
            pout[blockIdx.x * 2 + 1] = rs[0][1] + rs[1][1] + rs[2][1] + rs[3][1];
        }
    }
}

// ---------------- final LN + transpose out (B,L,C) -> (B,C,L) ----------------
// Consumes k_ln's per-block partials (contiguous: batch b owns entries [b*512, b*512+512)).
__global__ __launch_bounds__(256) void k_ln_t(const float* __restrict__ in,
                                              const float* __restrict__ g,
                                              const float* __restrict__ be,
                                              const float* __restrict__ pin,
                                              float* __restrict__ out) {
    __shared__ float tr[64][65];   // [c][l]
    __shared__ float rs[4][2];
    int l0 = blockIdx.x * 64, c0 = blockIdx.y * 64, b = blockIdx.z;
    int tid = threadIdx.x, r = tid >> 2, q = tid & 3;
    float s  = pin[(b * 512 + tid) * 2 + 0] + pin[(b * 512 + 256 + tid) * 2 + 0];
    float s2 = pin[(b * 512 + tid) * 2 + 1] + pin[(b * 512 + 256 + tid) * 2 + 1];
    s = wred_sum(s); s2 = wred_sum(s2);
    if ((tid & 63) == 0) { rs[tid >> 6][0] = s; rs[tid >> 6][1] = s2; }
    __syncthreads();
    float S = rs[0][0] + rs[1][0] + rs[2][0] + rs[3][0];
    float S2 = rs[0][1] + rs[1][1] + rs[2][1] + rs[3][1];
    float mean = S / (float)(CC * LL);
    float inv  = rsqrtf(S2 / (float)(CC * LL) - mean * mean + EPSV);
#pragma unroll
    for (int p = 0; p < 4; ++p) {
        int cc = 4 * (q + 4 * p);
        float4 v  = *(const float4*)&in[((size_t)(b * LL + l0 + r)) * CC + c0 + cc];
        float4 gg = *(const float4*)&g[c0 + cc];
        float4 bb = *(const float4*)&be[c0 + cc];
        tr[cc + 0][r] = (v.x - mean) * inv * gg.x + bb.x;
        tr[cc + 1][r] = (v.y - mean) * inv * gg.y + bb.y;
        tr[cc + 2][r] = (v.z - mean) * inv * gg.z + bb.z;
        tr[cc + 3][r] = (v.w - mean) * inv * gg.w + bb.w;
    }
    __syncthreads();
#pragma unroll
    for (int p = 0; p < 4; ++p) {
        int ll = 4 * (q + 4 * p);
        float4 v = *(const float4*)&tr[r][ll];
        *(float4*)&out[((size_t)(b * CC + c0 + r)) * LL + l0 + ll] = v;
    }
}

// ---------------- launch ----------------
extern "C" void kernel_launch(void* const* d_in, const int* in_sizes, int n_in,
                              void* d_out, int out_size, void* d_ws, size_t ws_size,
                              hipStream_t stream) {
    const float* x      = (const float*)d_in[0];
    const float* Wq     = (const float*)d_in[1];
    const float* bq     = (const float*)d_in[2];
    const float* Wk     = (const float*)d_in[3];
    const float* bk     = (const float*)d_in[4];
    const float* Wv     = (const float*)d_in[5];
    const float* bv     = (const float*)d_in[6];
    const float* Wo     = (const float*)d_in[7];
    const float* bo     = (const float*)d_in[8];
    const float* g_mha  = (const float*)d_in[9];
    const float* b_mha  = (const float*)d_in[10];
    const float* conv_w = (const float*)d_in[11];
    const float* conv_b = (const float*)d_in[12];
    const float* g_ffn  = (const float*)d_in[13];
    const float* b_ffn  = (const float*)d_in[14];
    const float* alpha  = (const float*)d_in[15];
    const float* g_out  = (const float*)d_in[16];
    const float* b_out  = (const float*)d_in[17];
    float* out = (float*)d_out;

    // workspace layout (float units) — no overlaps (obuf race from r3 fixed):
    float* ws = (float*)d_ws;
    float* t             = ws;                               // [0, 1,048,576)
    unsigned short* tb   = (unsigned short*)(ws + 1048576);  // [1,048,576, 1,572,864)
    unsigned short* QKVb = (unsigned short*)(ws + 1572864);  // [1,572,864, 4,718,592) 3x2M bf16
    float* f             = ws + 1572864;                     // reuse QKV (dead after attn)
    unsigned short* ybf  = (unsigned short*)(ws + 2621440);  // reuse QKV (dead after attn)
    unsigned short* obuf = (unsigned short*)(ws + 4718592);  // [4,718,592, 5,767,168)
    unsigned short* Wqkvb= (unsigned short*)(ws + 5767168);  // 393216 bf16 = 196,608 f
    unsigned short* Wob  = (unsigned short*)(ws + 5963776);  // 131072 bf16 = 65,536 f
    unsigned short* Wcb  = (unsigned short*)(ws + 6029312);  // 65536 bf16 = 32,768 f
    float* pstatA        = ws + 6062080;                     // 512 f (out-proj partials)
    float* pstatB        = ws + 6062592;                     // 512 f (conv partials)
    float* pstatC        = ws + 6063104;                     // 2048 f (ln2 partials)
                                                             // ends 6,065,152 f = 24.3 MB

    dim3 gtile(LL / 64, CC / 64, BB);        // 32,4,2
    k_prep<<<gtile, 256, 0, stream>>>(x, t, tb);
    k_cvtw<<<576, 256, 0, stream>>>(Wq, Wk, Wv, Wo, conv_w, Wqkvb, Wob, Wcb);

    dim3 gqkv(BLQ / 64, 1536 / 64);          // 64,24
    k_mm<<<gqkv, 256, 0, stream>>>(tb, Wqkvb, bq, bk, bv, nullptr, nullptr, QKVb,
                                   nullptr, 1, BLQ, 1536, CC);

    dim3 gattn(LL / 64, HH, BB);             // 32,8,2
    k_attn<<<gattn, 256, 0, stream>>>(QKVb, obuf);

    dim3 go(BLQ / 64, CC / 64);              // 64,4
    k_mm<<<go, 256, 0, stream>>>(obuf, Wob, bo, nullptr, nullptr, t, t, nullptr,
                                 pstatA, 0, BLQ, CC, HDIM);      // t += o@Wo^T+bo, stats

    k_ln<<<1024, 256, 0, stream>>>(t, g_mha, b_mha, pstatA, nullptr, nullptr,
                                   t, ybf, nullptr);             // y := ln(t), + bf16

    k_mm<<<go, 256, 0, stream>>>(ybf, Wcb, conv_b, nullptr, nullptr, nullptr, f, nullptr,
                                 pstatB, 0, BLQ, CC, CC);        // f = y@Wc^T+bc, stats

    k_ln<<<1024, 256, 0, stream>>>(f, g_ffn, b_ffn, pstatB, t, alpha,
                                   f, nullptr, pstatC);          // f := prelu(ln(f)) + y, stats

    k_ln_t<<<gtile, 256, 0, stream>>>(f, g_out, b_out, pstatC, out);
}